// Round 7
// baseline (225.019 us; speedup 1.0000x reference)
//
#include <hip/hip_runtime.h>

#define N_NODES 10000
#define BATCH   8
#define IN_SZ   64
#define UNITS   64
#define WIDTH   512            // IN_SZ * BATCH (bf16 elements per node row)
#define ROW_U   256            // uints per bf16 row (512 bf16)

typedef unsigned int uint;
typedef __attribute__((ext_vector_type(8))) short short8;
typedef __attribute__((ext_vector_type(4))) float float4v;
typedef __attribute__((ext_vector_type(2))) float float2v;
typedef __attribute__((ext_vector_type(2))) uint uint2v;

// ---- bf16 helpers (RNE) ----------------------------------------------------
__device__ inline float bf_lo(uint u) { return __uint_as_float(u << 16); }
__device__ inline float bf_hi(uint u) { return __uint_as_float(u & 0xFFFF0000u); }
__device__ inline uint  f2bf_bits(float f) {
    uint u = __float_as_uint(f);
    uint r = ((u >> 16) & 1u) + 0x7FFFu;
    return (u + r) >> 16;
}
__device__ inline uint pack2(float a, float b) {
    return f2bf_bits(a) | (f2bf_bits(b) << 16);
}

// ---------------------------------------------------------------------------
// k_transpose_hist: in[b, n*64+i] (fp32, nt load) -> x0[n, b*64+i] (bf16).
// Pure coalesced copy; also CSR row histogram (counts pre-zeroed).
// ---------------------------------------------------------------------------
__global__ __launch_bounds__(256) void k_transpose_hist(const float2v* __restrict__ in2,
                                                        uint* __restrict__ x0,
                                                        const int* __restrict__ rows,
                                                        int* __restrict__ counts,
                                                        int nnz) {
    int gid = blockIdx.x * 256 + threadIdx.x;      // uint index, 2,560,000 total
    if (gid < nnz) atomicAdd(&counts[rows[gid]], 1);
    int n  = gid >> 8;          // /256 uints per row
    int b  = (gid >> 5) & 7;    // 32 uints per (n,b) chunk
    int iu = gid & 31;
    float2v v = __builtin_nontemporal_load(&in2[(size_t)b * (N_NODES * 32) +
                                                (size_t)n * 32 + iu]);
    x0[gid] = pack2(v.x, v.y);
}

// ---------------------------------------------------------------------------
// k_scan: single block, 256 threads, serial chunk + wave shfl-scan.
// Zeroes counts for reuse as scatter cursors.
// ---------------------------------------------------------------------------
#define CHUNK 40
__global__ __launch_bounds__(256) void k_scan(int* __restrict__ counts,
                                              int* __restrict__ row_ptr, int n) {
    __shared__ int wsum[4];
    int t    = threadIdx.x;
    int base = t * CHUNK;
    int local[CHUNK];
    int tot = 0;
#pragma unroll
    for (int j = 0; j < CHUNK; ++j) {
        int idx = base + j;
        int v   = (idx < n) ? counts[idx] : 0;
        if (idx < n) counts[idx] = 0;
        local[j] = v;
        tot += v;
    }
    int lane = t & 63, w = t >> 6;
    int s = tot;
#pragma unroll
    for (int off = 1; off < 64; off <<= 1) {
        int nv = __shfl_up(s, off);
        if (lane >= off) s += nv;
    }
    if (lane == 63) wsum[w] = s;
    __syncthreads();
    int woff = 0;
    for (int k = 0; k < 4; ++k) if (k < w) woff += wsum[k];
    int run = woff + s - tot;
#pragma unroll
    for (int j = 0; j < CHUNK; ++j) {
        int idx = base + j;
        if (idx < n) row_ptr[idx] = run;
        run += local[j];
    }
    if (t == 255) row_ptr[n] = woff + s;
}

// ---------------------------------------------------------------------------
// k_scatter: scatter COO edges into CSR order as packed (col, val) uint2v.
// ---------------------------------------------------------------------------
__global__ __launch_bounds__(256) void k_scatter(const int* __restrict__ rows,
                                                 const int* __restrict__ cols,
                                                 const float* __restrict__ vals,
                                                 const int* __restrict__ row_ptr,
                                                 int* __restrict__ cursor,
                                                 uint2v* __restrict__ edges, int nnz) {
    int e = blockIdx.x * 256 + threadIdx.x;
    if (e >= nnz) return;
    int r   = rows[e];
    int pos = row_ptr[r] + atomicAdd(&cursor[r], 1);
    uint2v ev;
    ev.x = (uint)cols[e];
    ev.y = __float_as_uint(vals[e]);
    edges[pos] = ev;
}

// ---------------------------------------------------------------------------
// k_spmm: one WAVE per (row, column-quarter); lane owns one uint (2 bf16
// cols). Quarter read-set = 2.5 MB -> L2-resident per XCD. All NON-gather
// traffic (edge list, xsub, output) is nontemporal so it cannot evict the
// gather read-set (round-3 FETCH=56MB vs 10MB ideal was write/edge thrash).
// Edge list zero-padded to groups of 8: 8 independent loads in flight.
// ---------------------------------------------------------------------------
__global__ __launch_bounds__(256) void k_spmm(const int* __restrict__ row_ptr,
                                              const uint2v* __restrict__ edges,
                                              const uint* __restrict__ xin,
                                              uint* __restrict__ xout,
                                              const uint* __restrict__ xsub,
                                              float scale) {
    int wave  = threadIdx.x >> 6;
    int lane  = threadIdx.x & 63;
    int row   = blockIdx.x * 4 + wave;
    int col_u = blockIdx.y * 64 + lane;        // uint column (of 256 per row)

    int start = row_ptr[row];
    int end   = row_ptr[row + 1];
    float alo = 0.f, ahi = 0.f;

    for (int base = start; base < end; base += 64) {
        int e = base + lane;
        uint2v ev; ev.x = 0u; ev.y = 0u;
        if (e < end) ev = __builtin_nontemporal_load(&edges[e]);   // pad: col=0, val=0
        int cnt = min(64, end - base);
        cnt = (cnt + 7) & ~7;                  // zero-padded groups of 8
        for (int j0 = 0; j0 < cnt; j0 += 8) {
            int   c[8];
            float v[8];
            uint  x[8];
#pragma unroll
            for (int j = 0; j < 8; ++j) {
                c[j] = __builtin_amdgcn_readlane((int)ev.x, j0 + j);
                v[j] = __uint_as_float(__builtin_amdgcn_readlane((int)ev.y, j0 + j));
            }
#pragma unroll
            for (int j = 0; j < 8; ++j)
                x[j] = xin[(size_t)c[j] * ROW_U + col_u];
#pragma unroll
            for (int j = 0; j < 8; ++j) {
                alo += v[j] * bf_lo(x[j]);
                ahi += v[j] * bf_hi(x[j]);
            }
        }
    }

    float olo = scale * alo, ohi = scale * ahi;
    if (xsub) {
        uint sx = __builtin_nontemporal_load(&xsub[(size_t)row * ROW_U + col_u]);
        olo -= bf_lo(sx);
        ohi -= bf_hi(sx);
    }
    __builtin_nontemporal_store(pack2(olo, ohi), &xout[(size_t)row * ROW_U + col_u]);
}

// ---------------------------------------------------------------------------
// k_combine (MFMA): out[b,n,u] = bias[u] + sum_k A[(b,n), k] * Wp[k, u].
// Grid = (157, 8): blockIdx.y = batch b, so waves = 157*8*4 = 5024
// (~4.9/SIMD) instead of round-5's 628 (0.6/SIMD) -> A-load latency hidden
// by TLP. B frags read from LDS inline (no persistent 96-VGPR array);
// A loads and out stores nontemporal (read/written exactly once).
// ---------------------------------------------------------------------------
__global__ __launch_bounds__(256) void k_combine(const uint* __restrict__ x0,
                                                 const uint* __restrict__ x1,
                                                 const uint* __restrict__ x2,
                                                 const float* __restrict__ W,
                                                 const float* __restrict__ bias,
                                                 float* __restrict__ out) {
    __shared__ unsigned short sWt[64][200];    // [u][k] bf16, pad 192->200 (25.6 KB)
    int t = threadIdx.x;
    for (int e = t; e < 192 * 64; e += 256) {
        int f = e >> 6;                        // fan_in row = i*3 + m
        int u = e & 63;
        int i = f / 3;
        int m = f - 3 * i;
        sWt[u][m * 64 + i] = (unsigned short)f2bf_bits(W[e]);
    }
    __syncthreads();

    int wave = t >> 6, lane = t & 63;
    int mrow = lane & 15, quad = lane >> 4;
    int n0   = blockIdx.x * 64 + wave * 16;
    int b    = blockIdx.y;

    const uint* xs[3] = {x0, x1, x2};
    int an = n0 + mrow;
    if (an > N_NODES - 1) an = N_NODES - 1;    // clamp tail reads

    // prefetch all 6 A fragments (independent, in flight together)
    short8 af[6];
#pragma unroll
    for (int kb = 0; kb < 6; ++kb) {
        int mat = kb >> 1;
        int i0  = (kb & 1) * 32;
        af[kb] = __builtin_nontemporal_load(
            (const short8*)(xs[mat] + (size_t)an * ROW_U + b * 32 + i0 / 2 + quad * 4));
    }

    float4v acc[4];
#pragma unroll
    for (int ut = 0; ut < 4; ++ut) acc[ut] = (float4v){0.f, 0.f, 0.f, 0.f};

#pragma unroll
    for (int kb = 0; kb < 6; ++kb)
#pragma unroll
        for (int ut = 0; ut < 4; ++ut)
            acc[ut] = __builtin_amdgcn_mfma_f32_16x16x32_bf16(
                af[kb],
                *(const short8*)&sWt[ut * 16 + mrow][kb * 32 + quad * 8],
                acc[ut], 0, 0, 0);

#pragma unroll
    for (int ut = 0; ut < 4; ++ut) {
        float bv = bias[ut * 16 + mrow];
        int u = ut * 16 + mrow;
#pragma unroll
        for (int r = 0; r < 4; ++r) {
            int n = n0 + quad * 4 + r;
            if (n < N_NODES)
                __builtin_nontemporal_store(acc[ut][r] + bv,
                    &out[((size_t)b * N_NODES + n) * UNITS + u]);
        }
    }
}

// ---------------------------------------------------------------------------
extern "C" void kernel_launch(void* const* d_in, const int* in_sizes, int n_in,
                              void* d_out, int out_size, void* d_ws, size_t ws_size,
                              hipStream_t stream) {
    const float* inputs = (const float*)d_in[0];
    const int*   rows   = (const int*)d_in[1];
    const int*   cols   = (const int*)d_in[2];
    const float* vals   = (const float*)d_in[3];
    const float* W      = (const float*)d_in[4];
    const float* bias   = (const float*)d_in[5];
    float*       out    = (float*)d_out;
    int nnz = in_sizes[1];

    char* p = (char*)d_ws;
    auto alloc = [&](size_t bytes) {
        char* r = p;
        p += (bytes + 255) & ~(size_t)255;
        return r;
    };
    uint*   x0      = (uint*)alloc(sizeof(uint) * (size_t)N_NODES * ROW_U);
    uint*   x1      = (uint*)alloc(sizeof(uint) * (size_t)N_NODES * ROW_U);
    uint*   x2      = (uint*)alloc(sizeof(uint) * (size_t)N_NODES * ROW_U);
    int*    row_ptr = (int*)alloc(sizeof(int) * (N_NODES + 1));
    int*    cursor  = (int*)alloc(sizeof(int) * N_NODES);
    uint2v* edges   = (uint2v*)alloc(sizeof(uint2v) * (size_t)nnz);

    (void)hipMemsetAsync(cursor, 0, sizeof(int) * N_NODES, stream);
    k_transpose_hist<<<N_NODES, 256, 0, stream>>>((const float2v*)inputs, x0, rows,
                                                  cursor, nnz);
    k_scan<<<1, 256, 0, stream>>>(cursor, row_ptr, N_NODES);
    k_scatter<<<(nnz + 255) / 256, 256, 0, stream>>>(rows, cols, vals, row_ptr, cursor,
                                                     edges, nnz);
    dim3 sgrid(N_NODES / 4, 4);
    k_spmm<<<sgrid, 256, 0, stream>>>(row_ptr, edges, x0, x1, nullptr, 1.0f);
    k_spmm<<<sgrid, 256, 0, stream>>>(row_ptr, edges, x1, x2, x0, 2.0f);
    dim3 cgrid((N_NODES + 63) / 64, BATCH);
    k_combine<<<cgrid, 256, 0, stream>>>(x0, x1, x2, W, bias, out);
}

// Round 8
// 222.347 us; speedup vs baseline: 1.0120x; 1.0120x over previous
//
#include <hip/hip_runtime.h>

#define N_NODES 10000
#define BATCH   8
#define IN_SZ   64
#define UNITS   64
#define WIDTH   512            // IN_SZ * BATCH (bf16 elements per node row)
#define ROW_U   256            // uints per bf16 row (512 bf16)
#define ROW_U2  128            // uint2 per bf16 row

typedef unsigned int uint;
typedef __attribute__((ext_vector_type(8))) short short8;
typedef __attribute__((ext_vector_type(4))) float float4v;
typedef __attribute__((ext_vector_type(2))) float float2v;
typedef __attribute__((ext_vector_type(2))) uint uint2v;

// ---- bf16 helpers (RNE) ----------------------------------------------------
__device__ inline float bf_lo(uint u) { return __uint_as_float(u << 16); }
__device__ inline float bf_hi(uint u) { return __uint_as_float(u & 0xFFFF0000u); }
__device__ inline uint  f2bf_bits(float f) {
    uint u = __float_as_uint(f);
    uint r = ((u >> 16) & 1u) + 0x7FFFu;
    return (u + r) >> 16;
}
__device__ inline uint pack2(float a, float b) {
    return f2bf_bits(a) | (f2bf_bits(b) << 16);
}

// ---------------------------------------------------------------------------
// k_transpose_hist: in[b, n*64+i] (fp32, nt load) -> x0[n, b*64+i] (bf16).
// Pure coalesced copy; also CSR row histogram (counts pre-zeroed).
// ---------------------------------------------------------------------------
__global__ __launch_bounds__(256) void k_transpose_hist(const float2v* __restrict__ in2,
                                                        uint* __restrict__ x0,
                                                        const int* __restrict__ rows,
                                                        int* __restrict__ counts,
                                                        int nnz) {
    int gid = blockIdx.x * 256 + threadIdx.x;      // uint index, 2,560,000 total
    if (gid < nnz) atomicAdd(&counts[rows[gid]], 1);
    int n  = gid >> 8;          // /256 uints per row
    int b  = (gid >> 5) & 7;    // 32 uints per (n,b) chunk
    int iu = gid & 31;
    float2v v = __builtin_nontemporal_load(&in2[(size_t)b * (N_NODES * 32) +
                                                (size_t)n * 32 + iu]);
    x0[gid] = pack2(v.x, v.y);
}

// ---------------------------------------------------------------------------
// k_scan: single block, 256 threads, serial chunk + wave shfl-scan.
// Zeroes counts for reuse as scatter cursors.
// ---------------------------------------------------------------------------
#define CHUNK 40
__global__ __launch_bounds__(256) void k_scan(int* __restrict__ counts,
                                              int* __restrict__ row_ptr, int n) {
    __shared__ int wsum[4];
    int t    = threadIdx.x;
    int base = t * CHUNK;
    int local[CHUNK];
    int tot = 0;
#pragma unroll
    for (int j = 0; j < CHUNK; ++j) {
        int idx = base + j;
        int v   = (idx < n) ? counts[idx] : 0;
        if (idx < n) counts[idx] = 0;
        local[j] = v;
        tot += v;
    }
    int lane = t & 63, w = t >> 6;
    int s = tot;
#pragma unroll
    for (int off = 1; off < 64; off <<= 1) {
        int nv = __shfl_up(s, off);
        if (lane >= off) s += nv;
    }
    if (lane == 63) wsum[w] = s;
    __syncthreads();
    int woff = 0;
    for (int k = 0; k < 4; ++k) if (k < w) woff += wsum[k];
    int run = woff + s - tot;
#pragma unroll
    for (int j = 0; j < CHUNK; ++j) {
        int idx = base + j;
        if (idx < n) row_ptr[idx] = run;
        run += local[j];
    }
    if (t == 255) row_ptr[n] = woff + s;
}

// ---------------------------------------------------------------------------
// k_scatter: scatter COO edges into CSR order as packed (col, val) uint2v.
// ---------------------------------------------------------------------------
__global__ __launch_bounds__(256) void k_scatter(const int* __restrict__ rows,
                                                 const int* __restrict__ cols,
                                                 const float* __restrict__ vals,
                                                 const int* __restrict__ row_ptr,
                                                 int* __restrict__ cursor,
                                                 uint2v* __restrict__ edges, int nnz) {
    int e = blockIdx.x * 256 + threadIdx.x;
    if (e >= nnz) return;
    int r   = rows[e];
    int pos = row_ptr[r] + atomicAdd(&cursor[r], 1);
    uint2v ev;
    ev.x = (uint)cols[e];
    ev.y = __float_as_uint(vals[e]);
    edges[pos] = ev;
}

// ---------------------------------------------------------------------------
// k_spmm: one WAVE per (row, column-HALF); lane owns one uint2 (4 bf16
// cols) -> gather wave-load = 512 B (dwordx2), the minimum wave-load count
// (660k loads x 512 B = 338 MB logical). x8 independent loads in flight.
// Edge list / xsub / xout are nontemporal so the 5 MB half read-set keeps
// as much of the 4 MiB per-XCD L2 as possible.
// ---------------------------------------------------------------------------
__global__ __launch_bounds__(256) void k_spmm(const int* __restrict__ row_ptr,
                                              const uint2v* __restrict__ edges,
                                              const uint2v* __restrict__ xin,
                                              uint2v* __restrict__ xout,
                                              const uint2v* __restrict__ xsub,
                                              float scale) {
    int wave = threadIdx.x >> 6;
    int lane = threadIdx.x & 63;
    int row  = blockIdx.x * 4 + wave;
    int col2 = blockIdx.y * 64 + lane;         // uint2 column (of 128 per row)

    int start = row_ptr[row];
    int end   = row_ptr[row + 1];
    float a0 = 0.f, a1 = 0.f, a2 = 0.f, a3 = 0.f;

    for (int base = start; base < end; base += 64) {
        int e = base + lane;
        uint2v ev; ev.x = 0u; ev.y = 0u;
        if (e < end) ev = __builtin_nontemporal_load(&edges[e]);   // pad: col=0, val=0
        int cnt = min(64, end - base);
        cnt = (cnt + 7) & ~7;                  // zero-padded groups of 8
        for (int j0 = 0; j0 < cnt; j0 += 8) {
            int    c[8];
            float  v[8];
            uint2v x[8];
#pragma unroll
            for (int j = 0; j < 8; ++j) {
                c[j] = __builtin_amdgcn_readlane((int)ev.x, j0 + j);
                v[j] = __uint_as_float(__builtin_amdgcn_readlane((int)ev.y, j0 + j));
            }
#pragma unroll
            for (int j = 0; j < 8; ++j)
                x[j] = xin[(size_t)c[j] * ROW_U2 + col2];
#pragma unroll
            for (int j = 0; j < 8; ++j) {
                a0 += v[j] * bf_lo(x[j].x);
                a1 += v[j] * bf_hi(x[j].x);
                a2 += v[j] * bf_lo(x[j].y);
                a3 += v[j] * bf_hi(x[j].y);
            }
        }
    }

    float o0 = scale * a0, o1 = scale * a1, o2 = scale * a2, o3 = scale * a3;
    if (xsub) {
        uint2v sx = __builtin_nontemporal_load(&xsub[(size_t)row * ROW_U2 + col2]);
        o0 -= bf_lo(sx.x); o1 -= bf_hi(sx.x);
        o2 -= bf_lo(sx.y); o3 -= bf_hi(sx.y);
    }
    uint2v o;
    o.x = pack2(o0, o1);
    o.y = pack2(o2, o3);
    __builtin_nontemporal_store(o, &xout[(size_t)row * ROW_U2 + col2]);
}

// ---------------------------------------------------------------------------
// k_combine (MFMA): out[b,n,u] = bias[u] + sum_k A[(b,n), k] * Wp[k, u].
// Grid = (157, 8): blockIdx.y = batch b -> 5024 waves (~4.9/SIMD) for TLP.
// A loads / out stores nontemporal; B frags read from LDS inline.
// ---------------------------------------------------------------------------
__global__ __launch_bounds__(256) void k_combine(const uint* __restrict__ x0,
                                                 const uint* __restrict__ x1,
                                                 const uint* __restrict__ x2,
                                                 const float* __restrict__ W,
                                                 const float* __restrict__ bias,
                                                 float* __restrict__ out) {
    __shared__ unsigned short sWt[64][200];    // [u][k] bf16, pad 192->200 (25.6 KB)
    int t = threadIdx.x;
    for (int e = t; e < 192 * 64; e += 256) {
        int f = e >> 6;                        // fan_in row = i*3 + m
        int u = e & 63;
        int i = f / 3;
        int m = f - 3 * i;
        sWt[u][m * 64 + i] = (unsigned short)f2bf_bits(W[e]);
    }
    __syncthreads();

    int wave = t >> 6, lane = t & 63;
    int mrow = lane & 15, quad = lane >> 4;
    int n0   = blockIdx.x * 64 + wave * 16;
    int b    = blockIdx.y;

    const uint* xs[3] = {x0, x1, x2};
    int an = n0 + mrow;
    if (an > N_NODES - 1) an = N_NODES - 1;    // clamp tail reads

    short8 af[6];
#pragma unroll
    for (int kb = 0; kb < 6; ++kb) {
        int mat = kb >> 1;
        int i0  = (kb & 1) * 32;
        af[kb] = __builtin_nontemporal_load(
            (const short8*)(xs[mat] + (size_t)an * ROW_U + b * 32 + i0 / 2 + quad * 4));
    }

    float4v acc[4];
#pragma unroll
    for (int ut = 0; ut < 4; ++ut) acc[ut] = (float4v){0.f, 0.f, 0.f, 0.f};

#pragma unroll
    for (int kb = 0; kb < 6; ++kb)
#pragma unroll
        for (int ut = 0; ut < 4; ++ut)
            acc[ut] = __builtin_amdgcn_mfma_f32_16x16x32_bf16(
                af[kb],
                *(const short8*)&sWt[ut * 16 + mrow][kb * 32 + quad * 8],
                acc[ut], 0, 0, 0);

#pragma unroll
    for (int ut = 0; ut < 4; ++ut) {
        float bv = bias[ut * 16 + mrow];
        int u = ut * 16 + mrow;
#pragma unroll
        for (int r = 0; r < 4; ++r) {
            int n = n0 + quad * 4 + r;
            if (n < N_NODES)
                __builtin_nontemporal_store(acc[ut][r] + bv,
                    &out[((size_t)b * N_NODES + n) * UNITS + u]);
        }
    }
}

// ---------------------------------------------------------------------------
extern "C" void kernel_launch(void* const* d_in, const int* in_sizes, int n_in,
                              void* d_out, int out_size, void* d_ws, size_t ws_size,
                              hipStream_t stream) {
    const float* inputs = (const float*)d_in[0];
    const int*   rows   = (const int*)d_in[1];
    const int*   cols   = (const int*)d_in[2];
    const float* vals   = (const float*)d_in[3];
    const float* W      = (const float*)d_in[4];
    const float* bias   = (const float*)d_in[5];
    float*       out    = (float*)d_out;
    int nnz = in_sizes[1];

    char* p = (char*)d_ws;
    auto alloc = [&](size_t bytes) {
        char* r = p;
        p += (bytes + 255) & ~(size_t)255;
        return r;
    };
    uint*   x0      = (uint*)alloc(sizeof(uint) * (size_t)N_NODES * ROW_U);
    uint*   x1      = (uint*)alloc(sizeof(uint) * (size_t)N_NODES * ROW_U);
    uint*   x2      = (uint*)alloc(sizeof(uint) * (size_t)N_NODES * ROW_U);
    int*    row_ptr = (int*)alloc(sizeof(int) * (N_NODES + 1));
    int*    cursor  = (int*)alloc(sizeof(int) * N_NODES);
    uint2v* edges   = (uint2v*)alloc(sizeof(uint2v) * (size_t)nnz);

    (void)hipMemsetAsync(cursor, 0, sizeof(int) * N_NODES, stream);
    k_transpose_hist<<<N_NODES, 256, 0, stream>>>((const float2v*)inputs, x0, rows,
                                                  cursor, nnz);
    k_scan<<<1, 256, 0, stream>>>(cursor, row_ptr, N_NODES);
    k_scatter<<<(nnz + 255) / 256, 256, 0, stream>>>(rows, cols, vals, row_ptr, cursor,
                                                     edges, nnz);
    dim3 sgrid(N_NODES / 4, 2);
    k_spmm<<<sgrid, 256, 0, stream>>>(row_ptr, edges, (const uint2v*)x0,
                                      (uint2v*)x1, nullptr, 1.0f);
    k_spmm<<<sgrid, 256, 0, stream>>>(row_ptr, edges, (const uint2v*)x1,
                                      (uint2v*)x2, (const uint2v*)x0, 2.0f);
    dim3 cgrid((N_NODES + 63) / 64, BATCH);
    k_combine<<<cgrid, 256, 0, stream>>>(x0, x1, x2, W, bias, out);
}

// Round 9
// 221.647 us; speedup vs baseline: 1.0152x; 1.0032x over previous
//
#include <hip/hip_runtime.h>

#define N_NODES 10000
#define BATCH   8
#define IN_SZ   64
#define UNITS   64
#define WIDTH   512            // IN_SZ * BATCH (bf16 elements per node row)
#define ROW_U   256            // uints per bf16 row (512 bf16)
#define ROW_U2  128            // uint2 per bf16 row

typedef unsigned int uint;
typedef __attribute__((ext_vector_type(8))) short short8;
typedef __attribute__((ext_vector_type(4))) float float4v;
typedef __attribute__((ext_vector_type(2))) float float2v;
typedef __attribute__((ext_vector_type(2))) uint uint2v;

// ---- bf16 helpers (RNE) ----------------------------------------------------
__device__ inline float bf_lo(uint u) { return __uint_as_float(u << 16); }
__device__ inline float bf_hi(uint u) { return __uint_as_float(u & 0xFFFF0000u); }
__device__ inline uint  f2bf_bits(float f) {
    uint u = __float_as_uint(f);
    uint r = ((u >> 16) & 1u) + 0x7FFFu;
    return (u + r) >> 16;
}
__device__ inline uint pack2(float a, float b) {
    return f2bf_bits(a) | (f2bf_bits(b) << 16);
}

// ---------------------------------------------------------------------------
// k_transpose_hist: in[b, n*64+i] (fp32, nt load) -> x0[n, b*64+i] (bf16).
// Pure coalesced copy; also CSR row histogram (counts pre-zeroed).
// ---------------------------------------------------------------------------
__global__ __launch_bounds__(256) void k_transpose_hist(const float2v* __restrict__ in2,
                                                        uint* __restrict__ x0,
                                                        const int* __restrict__ rows,
                                                        int* __restrict__ counts,
                                                        int nnz) {
    int gid = blockIdx.x * 256 + threadIdx.x;      // uint index, 2,560,000 total
    if (gid < nnz) atomicAdd(&counts[rows[gid]], 1);
    int n  = gid >> 8;          // /256 uints per row
    int b  = (gid >> 5) & 7;    // 32 uints per (n,b) chunk
    int iu = gid & 31;
    float2v v = __builtin_nontemporal_load(&in2[(size_t)b * (N_NODES * 32) +
                                                (size_t)n * 32 + iu]);
    x0[gid] = pack2(v.x, v.y);
}

// ---------------------------------------------------------------------------
// k_scan: single block, 256 threads, serial chunk + wave shfl-scan.
// Prefix is over counts PADDED to a multiple of 8 (so each row's CSR
// segment is a whole number of 8-edge groups; pad slots hold col=0,val=0
// from the pre-memset edges buffer). Zeroes counts for reuse as cursors.
// ---------------------------------------------------------------------------
#define CHUNK 40
__global__ __launch_bounds__(256) void k_scan(int* __restrict__ counts,
                                              int* __restrict__ row_ptr, int n) {
    __shared__ int wsum[4];
    int t    = threadIdx.x;
    int base = t * CHUNK;
    int local[CHUNK];
    int tot = 0;
#pragma unroll
    for (int j = 0; j < CHUNK; ++j) {
        int idx = base + j;
        int v   = (idx < n) ? counts[idx] : 0;
        if (idx < n) counts[idx] = 0;
        int pv  = (v + 7) & ~7;               // padded segment length
        local[j] = pv;
        tot += pv;
    }
    int lane = t & 63, w = t >> 6;
    int s = tot;
#pragma unroll
    for (int off = 1; off < 64; off <<= 1) {
        int nv = __shfl_up(s, off);
        if (lane >= off) s += nv;
    }
    if (lane == 63) wsum[w] = s;
    __syncthreads();
    int woff = 0;
    for (int k = 0; k < 4; ++k) if (k < w) woff += wsum[k];
    int run = woff + s - tot;
#pragma unroll
    for (int j = 0; j < CHUNK; ++j) {
        int idx = base + j;
        if (idx < n) row_ptr[idx] = run;
        run += local[j];
    }
    if (t == 255) row_ptr[n] = woff + s;
}

// ---------------------------------------------------------------------------
// k_scatter: scatter COO edges into padded-CSR order as (col, val) uint2v.
// Pad slots keep their memset value (0,0) -> zero contribution in spmm.
// ---------------------------------------------------------------------------
__global__ __launch_bounds__(256) void k_scatter(const int* __restrict__ rows,
                                                 const int* __restrict__ cols,
                                                 const float* __restrict__ vals,
                                                 const int* __restrict__ row_ptr,
                                                 int* __restrict__ cursor,
                                                 uint2v* __restrict__ edges, int nnz) {
    int e = blockIdx.x * 256 + threadIdx.x;
    if (e >= nnz) return;
    int r   = rows[e];
    int pos = row_ptr[r] + atomicAdd(&cursor[r], 1);
    uint2v ev;
    ev.x = (uint)cols[e];
    ev.y = __float_as_uint(vals[e]);
    edges[pos] = ev;
}

// ---------------------------------------------------------------------------
// k_spmm: one WAVE per (row, column-half); lane owns one uint2 (4 bf16 cols).
// Edge metadata is WAVE-UNIFORM: segments are padded to x8, the loop index
// is uniform, so edges[e+j] compiles to scalar s_load (dwordx16 = 8 edges,
// one SMEM op, zero VALU) — no readlane, no per-lane edge loads, no tail
// branches. Gathers: 8 independent dwordx2 in flight, SGPR-base addressing.
// float2v accumulators -> v_pk_fma_f32 (2 FMAs/inst).
// ---------------------------------------------------------------------------
__global__ __launch_bounds__(256) void k_spmm(const int* __restrict__ row_ptr,
                                              const uint2v* __restrict__ edges,
                                              const uint2v* __restrict__ xin,
                                              uint2v* __restrict__ xout,
                                              const uint2v* __restrict__ xsub,
                                              float scale) {
    int wave = threadIdx.x >> 6;
    int lane = threadIdx.x & 63;
    int row  = blockIdx.x * 4 + wave;
    int col2 = blockIdx.y * 64 + lane;         // uint2 column (of 128 per row)

    int start = __builtin_amdgcn_readfirstlane(row_ptr[row]);
    int end   = __builtin_amdgcn_readfirstlane(row_ptr[row + 1]);

    float2v accA = {0.f, 0.f};                 // (lo, hi) of .x
    float2v accB = {0.f, 0.f};                 // (lo, hi) of .y

    for (int e = start; e < end; e += 8) {
        uint2v ev[8];
#pragma unroll
        for (int j = 0; j < 8; ++j) ev[j] = edges[e + j];   // uniform -> s_load
        uint2v x[8];
#pragma unroll
        for (int j = 0; j < 8; ++j)
            x[j] = xin[(size_t)ev[j].x * ROW_U2 + col2];
#pragma unroll
        for (int j = 0; j < 8; ++j) {
            float vj = __uint_as_float(ev[j].y);
            float2v vv = {vj, vj};
            float2v pA = {bf_lo(x[j].x), bf_hi(x[j].x)};
            float2v pB = {bf_lo(x[j].y), bf_hi(x[j].y)};
            accA += vv * pA;
            accB += vv * pB;
        }
    }

    float o0 = scale * accA.x, o1 = scale * accA.y;
    float o2 = scale * accB.x, o3 = scale * accB.y;
    if (xsub) {
        uint2v sx = __builtin_nontemporal_load(&xsub[(size_t)row * ROW_U2 + col2]);
        o0 -= bf_lo(sx.x); o1 -= bf_hi(sx.x);
        o2 -= bf_lo(sx.y); o3 -= bf_hi(sx.y);
    }
    uint2v o;
    o.x = pack2(o0, o1);
    o.y = pack2(o2, o3);
    __builtin_nontemporal_store(o, &xout[(size_t)row * ROW_U2 + col2]);
}

// ---------------------------------------------------------------------------
// k_combine (MFMA): out[b,n,u] = bias[u] + sum_k A[(b,n), k] * Wp[k, u].
// Grid = (157, 8): blockIdx.y = batch b -> 5024 waves (~4.9/SIMD) for TLP.
// A loads / out stores nontemporal; B frags read from LDS inline.
// ---------------------------------------------------------------------------
__global__ __launch_bounds__(256) void k_combine(const uint* __restrict__ x0,
                                                 const uint* __restrict__ x1,
                                                 const uint* __restrict__ x2,
                                                 const float* __restrict__ W,
                                                 const float* __restrict__ bias,
                                                 float* __restrict__ out) {
    __shared__ unsigned short sWt[64][200];    // [u][k] bf16, pad 192->200 (25.6 KB)
    int t = threadIdx.x;
    for (int e = t; e < 192 * 64; e += 256) {
        int f = e >> 6;                        // fan_in row = i*3 + m
        int u = e & 63;
        int i = f / 3;
        int m = f - 3 * i;
        sWt[u][m * 64 + i] = (unsigned short)f2bf_bits(W[e]);
    }
    __syncthreads();

    int wave = t >> 6, lane = t & 63;
    int mrow = lane & 15, quad = lane >> 4;
    int n0   = blockIdx.x * 64 + wave * 16;
    int b    = blockIdx.y;

    const uint* xs[3] = {x0, x1, x2};
    int an = n0 + mrow;
    if (an > N_NODES - 1) an = N_NODES - 1;    // clamp tail reads

    short8 af[6];
#pragma unroll
    for (int kb = 0; kb < 6; ++kb) {
        int mat = kb >> 1;
        int i0  = (kb & 1) * 32;
        af[kb] = __builtin_nontemporal_load(
            (const short8*)(xs[mat] + (size_t)an * ROW_U + b * 32 + i0 / 2 + quad * 4));
    }

    float4v acc[4];
#pragma unroll
    for (int ut = 0; ut < 4; ++ut) acc[ut] = (float4v){0.f, 0.f, 0.f, 0.f};

#pragma unroll
    for (int kb = 0; kb < 6; ++kb)
#pragma unroll
        for (int ut = 0; ut < 4; ++ut)
            acc[ut] = __builtin_amdgcn_mfma_f32_16x16x32_bf16(
                af[kb],
                *(const short8*)&sWt[ut * 16 + mrow][kb * 32 + quad * 8],
                acc[ut], 0, 0, 0);

#pragma unroll
    for (int ut = 0; ut < 4; ++ut) {
        float bv = bias[ut * 16 + mrow];
        int u = ut * 16 + mrow;
#pragma unroll
        for (int r = 0; r < 4; ++r) {
            int n = n0 + quad * 4 + r;
            if (n < N_NODES)
                __builtin_nontemporal_store(acc[ut][r] + bv,
                    &out[((size_t)b * N_NODES + n) * UNITS + u]);
        }
    }
}

// ---------------------------------------------------------------------------
extern "C" void kernel_launch(void* const* d_in, const int* in_sizes, int n_in,
                              void* d_out, int out_size, void* d_ws, size_t ws_size,
                              hipStream_t stream) {
    const float* inputs = (const float*)d_in[0];
    const int*   rows   = (const int*)d_in[1];
    const int*   cols   = (const int*)d_in[2];
    const float* vals   = (const float*)d_in[3];
    const float* W      = (const float*)d_in[4];
    const float* bias   = (const float*)d_in[5];
    float*       out    = (float*)d_out;
    int nnz = in_sizes[1];

    char* p = (char*)d_ws;
    auto alloc = [&](size_t bytes) {
        char* r = p;
        p += (bytes + 255) & ~(size_t)255;
        return r;
    };
    uint*   x0      = (uint*)alloc(sizeof(uint) * (size_t)N_NODES * ROW_U);
    uint*   x1      = (uint*)alloc(sizeof(uint) * (size_t)N_NODES * ROW_U);
    uint*   x2      = (uint*)alloc(sizeof(uint) * (size_t)N_NODES * ROW_U);
    int*    row_ptr = (int*)alloc(sizeof(int) * (N_NODES + 1));
    // cursor and edges adjacent: one memset zeroes both
    int*    cursor  = (int*)alloc(sizeof(int) * N_NODES);
    size_t  epad    = (size_t)nnz + 8 * N_NODES + 64;   // padded edge capacity
    uint2v* edges   = (uint2v*)alloc(sizeof(uint2v) * epad);
    size_t  zspan   = (char*)(edges + epad) - (char*)cursor;

    (void)hipMemsetAsync(cursor, 0, zspan, stream);
    k_transpose_hist<<<N_NODES, 256, 0, stream>>>((const float2v*)inputs, x0, rows,
                                                  cursor, nnz);
    k_scan<<<1, 256, 0, stream>>>(cursor, row_ptr, N_NODES);
    k_scatter<<<(nnz + 255) / 256, 256, 0, stream>>>(rows, cols, vals, row_ptr, cursor,
                                                     edges, nnz);
    dim3 sgrid(N_NODES / 4, 2);
    k_spmm<<<sgrid, 256, 0, stream>>>(row_ptr, edges, (const uint2v*)x0,
                                      (uint2v*)x1, nullptr, 1.0f);
    k_spmm<<<sgrid, 256, 0, stream>>>(row_ptr, edges, (const uint2v*)x1,
                                      (uint2v*)x2, (const uint2v*)x0, 2.0f);
    dim3 cgrid((N_NODES + 63) / 64, BATCH);
    k_combine<<<cgrid, 256, 0, stream>>>(x0, x1, x2, W, bias, out);
}